// Round 2
// baseline (7147.150 us; speedup 1.0000x reference)
//
#include <hip/hip_runtime.h>
#include <math.h>

#define B 8
#define C 64
#define L 2048
#define CS 256
#define BCL  (B*C*L)    // 1048576
#define BCSL (B*CS*L)   // 4194304
#define HS 0.25f

typedef unsigned short u16;
typedef unsigned int   u32;
typedef __attribute__((ext_vector_type(8))) short sh8;
typedef __attribute__((ext_vector_type(4))) float f4;

__device__ __forceinline__ float gelu(float x) {
    return 0.5f * x * (1.0f + erff(x * 0.70710678118654752440f));
}
__device__ __forceinline__ u16 f2b(float f) {
    u32 u = __float_as_uint(f);
    u32 r = u + 0x7FFFu + ((u >> 16) & 1u);
    return (u16)(r >> 16);
}
__device__ __forceinline__ float b2f(u16 h) {
    return __uint_as_float(((u32)h) << 16);
}

struct Combo6 { const float* p[6]; float c[6]; int n; };

// ---------- weight prep: fp32 [oc][ic][k] -> bf16 A-frag order ----------
// K enumeration: K = kk*IC + ic (k-major). frag idx: [chunk][ocg][lane][j]
__global__ __launch_bounds__(256) void prep_k(const float* __restrict__ w,
        u16* __restrict__ dst, int IC, int OC) {
    int idx = blockIdx.x * 256 + threadIdx.x;
    int OCG = OC >> 4;
    int j = idx & 7, lane = (idx >> 3) & 63, t = idx >> 9;
    int ocg = t % OCG, c = t / OCG;
    int oc = ocg * 16 + (lane & 15);
    int K = c * 32 + ((lane >> 4) & 3) * 8 + j;
    int kk = K / IC, ic = K % IC;
    dst[idx] = f2b(w[((size_t)oc * IC + ic) * 3 + kk]);
}

// ---------- all 25 cond vectors ----------
__global__ void cond25_k(const float* __restrict__ tw1, const float* __restrict__ tb1,
                         const float* __restrict__ tw2, const float* __restrict__ tb2,
                         const float* __restrict__ cw, const float* __restrict__ cb,
                         float* __restrict__ condall) {
    __shared__ float te1[16], te2[16];
    int tix = blockIdx.x;
    int tid = threadIdx.x;
    double add[6] = {0.0, 0.25/5.0, 3.0*0.25/10.0, 4.0*0.25/5.0, 8.0*0.25/9.0, 0.25};
    float t = (tix == 24) ? 1.0f : (float)((double)(tix / 6) * 0.25 + add[tix % 6]);
    if (tid < 16) te1[tid] = gelu(t * tw1[tid] + tb1[tid]);
    __syncthreads();
    if (tid < 16) {
        float s = tb2[tid];
        for (int k = 0; k < 16; ++k) s += te1[k] * tw2[tid*16+k];
        te2[tid] = s;
    }
    __syncthreads();
    float s = cb[tid];
    for (int j = 0; j < 16; ++j) s += te2[j] * cw[tid*16+j];
    condall[tix*128 + tid] = s;
}

// ---------- conv1: IC=256 fp32-combo in, FiLM+GELU, bf16 out ----------
// grid (64,8), block 256. tile 64oc x 32pos. K=768, 24 chunks.
__global__ __launch_bounds__(256) void conv1_k(Combo6 in, const u16* __restrict__ wp,
        const float* __restrict__ bias, const float* __restrict__ condall, int tix,
        u16* __restrict__ outH) {
    __shared__ u16 xs[34][264];
    const int tid = threadIdx.x;
    const int l0 = blockIdx.x * 32;
    const int b  = blockIdx.y;
    {   // stage combo -> bf16 transposed LDS; thread = one ic, loop positions
        const int ic = tid;
        size_t rb = ((size_t)b * CS + ic) * L;
        for (int r = 0; r < 34; ++r) {
            int gl = l0 - 1 + r;
            float v = 0.0f;
            if (gl >= 0 && gl < L) {
                size_t a = rb + gl;
                v = in.p[0][a];
                for (int t = 1; t < in.n; ++t) v += in.c[t] * in.p[t][a];
            }
            xs[r][ic] = f2b(v);
        }
    }
    __syncthreads();
    const int wave = tid >> 6, lane = tid & 63;
    const int nlo = lane & 15, quad = lane >> 4;
    f4 acc0 = {0.f,0.f,0.f,0.f}, acc1 = {0.f,0.f,0.f,0.f};
    const sh8* wp8 = (const sh8*)wp;
    for (int c = 0; c < 24; ++c) {
        int kk = c >> 3, ic0 = (c & 7) << 5;
        sh8 a  = wp8[(c * 4 + wave) * 64 + lane];
        sh8 b0 = *(const sh8*)&xs[nlo + kk][ic0 + quad * 8];
        sh8 b1 = *(const sh8*)&xs[16 + nlo + kk][ic0 + quad * 8];
        acc0 = __builtin_amdgcn_mfma_f32_16x16x32_bf16(a, b0, acc0, 0, 0, 0);
        acc1 = __builtin_amdgcn_mfma_f32_16x16x32_bf16(a, b1, acc1, 0, 0, 0);
    }
    const float* cd = condall + tix * 128;
    #pragma unroll
    for (int reg = 0; reg < 4; ++reg) {
        int oc = wave * 16 + quad * 4 + reg;
        float bv = bias[oc], g = cd[oc], be = cd[64 + oc];
        float v0 = (1.0f + g) * (acc0[reg] + bv) + be;
        float v1 = (1.0f + g) * (acc1[reg] + bv) + be;
        outH[((size_t)b * C + oc) * L + l0 + nlo]      = f2b(gelu(v0));
        outH[((size_t)b * C + oc) * L + l0 + 16 + nlo] = f2b(gelu(v1));
    }
}

// ---------- conv2: IC=64 bf16 in, GELU, bf16 out ----------
__global__ __launch_bounds__(256) void conv2_k(const u16* __restrict__ inH,
        const u16* __restrict__ wp, const float* __restrict__ bias,
        u16* __restrict__ outH) {
    __shared__ u16 xs[34][72];
    const int tid = threadIdx.x;
    const int l0 = blockIdx.x * 32;
    const int b  = blockIdx.y;
    {
        const int ic = tid & 63;
        size_t rb = ((size_t)b * C + ic) * L;
        for (int r = tid >> 6; r < 34; r += 4) {
            int gl = l0 - 1 + r;
            xs[r][ic] = (gl >= 0 && gl < L) ? inH[rb + gl] : (u16)0;
        }
    }
    __syncthreads();
    const int wave = tid >> 6, lane = tid & 63;
    const int nlo = lane & 15, quad = lane >> 4;
    f4 acc0 = {0.f,0.f,0.f,0.f}, acc1 = {0.f,0.f,0.f,0.f};
    const sh8* wp8 = (const sh8*)wp;
    #pragma unroll
    for (int c = 0; c < 6; ++c) {
        int kk = c >> 1, ic0 = (c & 1) << 5;
        sh8 a  = wp8[(c * 4 + wave) * 64 + lane];
        sh8 b0 = *(const sh8*)&xs[nlo + kk][ic0 + quad * 8];
        sh8 b1 = *(const sh8*)&xs[16 + nlo + kk][ic0 + quad * 8];
        acc0 = __builtin_amdgcn_mfma_f32_16x16x32_bf16(a, b0, acc0, 0, 0, 0);
        acc1 = __builtin_amdgcn_mfma_f32_16x16x32_bf16(a, b1, acc1, 0, 0, 0);
    }
    #pragma unroll
    for (int reg = 0; reg < 4; ++reg) {
        int oc = wave * 16 + quad * 4 + reg;
        float bv = bias[oc];
        outH[((size_t)b * C + oc) * L + l0 + nlo]      = f2b(gelu(acc0[reg] + bv));
        outH[((size_t)b * C + oc) * L + l0 + 16 + nlo] = f2b(gelu(acc1[reg] + bv));
    }
}

// ---------- conv3: IC=64 bf16 in, 256 oc, fp32 out; optional fused y-update ----------
template<bool YUP>
__global__ __launch_bounds__(256) void conv3_k(const u16* __restrict__ inH,
        const u16* __restrict__ wp, const float* __restrict__ bias,
        float* __restrict__ outS,
        float* __restrict__ y, const float* __restrict__ s1,
        const float* __restrict__ s3, const float* __restrict__ s4,
        const float* __restrict__ s5) {
    __shared__ u16 xs[34][72];
    const int tid = threadIdx.x;
    const int l0 = blockIdx.x * 32;
    const int b  = blockIdx.y;
    {
        const int ic = tid & 63;
        size_t rb = ((size_t)b * C + ic) * L;
        for (int r = tid >> 6; r < 34; r += 4) {
            int gl = l0 - 1 + r;
            xs[r][ic] = (gl >= 0 && gl < L) ? inH[rb + gl] : (u16)0;
        }
    }
    __syncthreads();
    const int wave = tid >> 6, lane = tid & 63;
    const int nlo = lane & 15, quad = lane >> 4;
    f4 acc[4][2];
    #pragma unroll
    for (int mf = 0; mf < 4; ++mf)
        #pragma unroll
        for (int nf = 0; nf < 2; ++nf) acc[mf][nf] = f4{0.f,0.f,0.f,0.f};
    const sh8* wp8 = (const sh8*)wp;
    #pragma unroll
    for (int c = 0; c < 6; ++c) {
        int kk = c >> 1, ic0 = (c & 1) << 5;
        sh8 b0 = *(const sh8*)&xs[nlo + kk][ic0 + quad * 8];
        sh8 b1 = *(const sh8*)&xs[16 + nlo + kk][ic0 + quad * 8];
        #pragma unroll
        for (int mf = 0; mf < 4; ++mf) {
            sh8 a = wp8[(c * 16 + wave * 4 + mf) * 64 + lane];
            acc[mf][0] = __builtin_amdgcn_mfma_f32_16x16x32_bf16(a, b0, acc[mf][0], 0, 0, 0);
            acc[mf][1] = __builtin_amdgcn_mfma_f32_16x16x32_bf16(a, b1, acc[mf][1], 0, 0, 0);
        }
    }
    const float c1 = HS * (35.f/384.f), c3 = HS * (500.f/1113.f),
                c4 = HS * (125.f/192.f), c5 = -HS * (2187.f/6784.f),
                c6 = HS * (11.f/84.f);
    #pragma unroll
    for (int mf = 0; mf < 4; ++mf) {
        #pragma unroll
        for (int nf = 0; nf < 2; ++nf) {
            #pragma unroll
            for (int reg = 0; reg < 4; ++reg) {
                int oc = (wave * 4 + mf) * 16 + quad * 4 + reg;
                int pos = l0 + nf * 16 + nlo;
                size_t idx = ((size_t)b * CS + oc) * L + pos;
                float v = acc[mf][nf][reg] + bias[oc];
                if (YUP) {
                    float yv = y[idx] + c1 * s1[idx] + c3 * s3[idx] + c4 * s4[idx]
                             + c5 * s5[idx] + c6 * v;
                    y[idx] = yv;
                } else {
                    outS[idx] = v;
                }
            }
        }
    }
}

// ---------- wavelet part (fp32, unchanged structure) ----------
__global__ __launch_bounds__(256) void rowmax_k(const float* __restrict__ a, float* __restrict__ bm) {
    __shared__ float red[256];
    int row = blockIdx.x;
    const float* p = a + (size_t)row * L;
    float m = -1e30f;
    for (int t = threadIdx.x; t < L; t += 256) m = fmaxf(m, p[t]);
    red[threadIdx.x] = m;
    __syncthreads();
    for (int s = 128; s > 0; s >>= 1) {
        if (threadIdx.x < s) red[threadIdx.x] = fmaxf(red[threadIdx.x], red[threadIdx.x + s]);
        __syncthreads();
    }
    if (threadIdx.x == 0) bm[row] = red[0];
}

__global__ __launch_bounds__(256) void mlp_k(const float* __restrict__ bm,
    const float* __restrict__ sw1, const float* __restrict__ sb1,
    const float* __restrict__ sw2, const float* __restrict__ sb2,
    const float* __restrict__ sw3, const float* __restrict__ sb3,
    float* __restrict__ filt) {
    __shared__ float m[8][64], f1[8][32], f2[8][32], raw[8][16], nrm[8][2];
    int tid = threadIdx.x;
    for (int i = tid; i < 512; i += 256) m[i >> 6][i & 63] = bm[i];
    __syncthreads();
    {
        int b = tid >> 5, h = tid & 31;
        float s = sb1[h];
        for (int c = 0; c < 64; ++c) s += m[b][c] * sw1[h*64+c];
        f1[b][h] = gelu(s);
    }
    __syncthreads();
    {
        int b = tid >> 5, h = tid & 31;
        float s = sb2[h];
        for (int k = 0; k < 32; ++k) s += f1[b][k] * sw2[h*32+k];
        f2[b][h] = gelu(s);
    }
    __syncthreads();
    if (tid < 128) {
        int b = tid >> 4, j = tid & 15;
        float s = sb3[j];
        for (int k = 0; k < 32; ++k) s += f2[b][k] * sw3[j*32+k];
        raw[b][j] = s;
    }
    __syncthreads();
    if (tid < 16) {
        int b = tid >> 1, half = tid & 1;
        float s = 0.f;
        for (int j = 0; j < 8; ++j) { float v = raw[b][half*8+j]; s += v*v; }
        nrm[b][half] = sqrtf(s);
    }
    __syncthreads();
    if (tid < 16) {
        int half = tid >> 3;
        float s = 0.f;
        for (int b = 0; b < 8; ++b) s += raw[b][tid] / nrm[b][half];
        filt[tid] = s * 0.125f;
    }
}

__global__ __launch_bounds__(256) void wconv_k(const float* __restrict__ ap,
    const float* __restrict__ filt, float* __restrict__ apOut,
    float* __restrict__ stacked, int lev) {
    __shared__ float f[16];
    if (threadIdx.x < 16) f[threadIdx.x] = filt[threadIdx.x];
    __syncthreads();
    size_t idx = (size_t)blockIdx.x * 256 + threadIdx.x;
    int l = (int)(idx & 2047);
    size_t bc = idx >> 11;
    int c = (int)(bc & 63), b = (int)(bc >> 6);
    const float* row = ap + (bc << 11);
    float lo = 0.f, hi = 0.f;
    #pragma unroll
    for (int k = 0; k < 8; ++k) {
        int mI = l + k - 3;
        mI = mI < 0 ? -mI : (mI >= L ? 2*L - 2 - mI : mI);
        float v = row[mI];
        lo += v * f[k];
        hi += v * f[8+k];
    }
    apOut[idx] = lo;
    stacked[((size_t)b * CS + (size_t)(lev+1) * 64 + c) * L + l] = hi;
}

__global__ __launch_bounds__(256) void copyx_k(const float* __restrict__ x, float* __restrict__ st) {
    size_t i = (size_t)blockIdx.x * 256 + threadIdx.x;
    size_t b = i >> 17, rem = i & 131071;
    st[b * ((size_t)CS*L) + rem] = x[i];
}

__global__ __launch_bounds__(256) void copy4_k(const float* __restrict__ s, float* __restrict__ d) {
    size_t i = (size_t)blockIdx.x * 256 + threadIdx.x;
    ((float4*)d)[i] = ((const float4*)s)[i];
}

// ---------- ecloss ----------
__global__ __launch_bounds__(256) void ecred_k(const float* __restrict__ st,
        const float* __restrict__ dx, double* __restrict__ inner) {
    __shared__ double red[256];
    size_t base = (size_t)blockIdx.x * 4096;
    double s = 0.0;
    for (int t = threadIdx.x; t < 4096; t += 256)
        s += (double)st[base + t] * (double)dx[base + t];
    red[threadIdx.x] = s;
    __syncthreads();
    for (int k = 128; k > 0; k >>= 1) {
        if (threadIdx.x < k) red[threadIdx.x] += red[threadIdx.x + k];
        __syncthreads();
    }
    if (threadIdx.x == 0) atomicAdd(&inner[blockIdx.x >> 7], red[0]);
}

__global__ void ecfin_k(const double* __restrict__ inner, float* __restrict__ out) {
    double s = 0.0;
    for (int b = 0; b < 8; ++b) s += inner[b] * inner[b];
    out[BCSL] = (float)(s / 8.0);
}

__global__ __launch_bounds__(256) void gather_k(const float* __restrict__ y, float* __restrict__ out) {
    size_t q = (size_t)blockIdx.x * 256 + threadIdx.x;
    int l4 = (int)(q & 511);
    int c  = (int)((q >> 9) & 63);
    int b  = (int)((q >> 15) & 7);
    int j  = (int)(q >> 18);
    ((float4*)out)[q] = ((const float4*)y)[((size_t)b * CS + (size_t)j * 64 + c) * 512 + l4];
}

extern "C" void kernel_launch(void* const* d_in, const int* in_sizes, int n_in,
                              void* d_out, int out_size, void* d_ws, size_t ws_size,
                              hipStream_t stream) {
    const float* x   = (const float*)d_in[0];
    const float* sw1 = (const float*)d_in[1];
    const float* sb1 = (const float*)d_in[2];
    const float* sw2 = (const float*)d_in[3];
    const float* sb2 = (const float*)d_in[4];
    const float* sw3 = (const float*)d_in[5];
    const float* sb3 = (const float*)d_in[6];
    const float* tw1 = (const float*)d_in[7];
    const float* tb1 = (const float*)d_in[8];
    const float* tw2 = (const float*)d_in[9];
    const float* tb2 = (const float*)d_in[10];
    const float* cw  = (const float*)d_in[11];
    const float* cb  = (const float*)d_in[12];
    const float* k1  = (const float*)d_in[13];
    const float* kb1 = (const float*)d_in[14];
    const float* k2  = (const float*)d_in[15];
    const float* kb2 = (const float*)d_in[16];
    const float* k3  = (const float*)d_in[17];
    const float* kb3 = (const float*)d_in[18];
    float* out = (float*)d_out;

    float* ws = (float*)d_ws;
    float* stacked = ws;                 // BCSL
    float* y    = stacked + BCSL;        // BCSL
    float* s1   = y  + BCSL;
    float* s2   = s1 + BCSL;
    float* s3   = s2 + BCSL;
    float* s4   = s3 + BCSL;
    float* s5   = s4 + BCSL;
    float* cond = s5 + BCSL;             // 25*128
    float* bmax = cond + 3200;           // 512
    float* filt = bmax + 512;            // 16
    double* inner = (double*)(filt + 16);            // 8 doubles (16 floats)
    u16* h1  = (u16*)(filt + 32);                    // BCL
    u16* h2  = h1 + BCL;                             // BCL
    u16* wp1 = h2 + BCL;                             // 49152
    u16* wp2 = wp1 + 49152;                          // 12288
    u16* wp3 = wp2 + 12288;                          // 49152

    hipMemsetAsync(inner, 0, 8 * sizeof(double), stream);

    // weight prep + cond table
    prep_k<<<192, 256, 0, stream>>>(k1, wp1, CS, C);
    prep_k<<<48,  256, 0, stream>>>(k2, wp2, C,  C);
    prep_k<<<192, 256, 0, stream>>>(k3, wp3, C,  CS);
    cond25_k<<<25, 128, 0, stream>>>(tw1, tb1, tw2, tb2, cw, cb, cond);

    // wavelet decomposition (s2/s3 used as fp32 scratch before ODE)
    copyx_k<<<4096, 256, 0, stream>>>(x, stacked);
    const float* apIn = x;
    float* apBuf[2] = {s2, s3};
    for (int lev = 0; lev < 3; ++lev) {
        rowmax_k<<<512, 256, 0, stream>>>(apIn, bmax);
        mlp_k<<<1, 256, 0, stream>>>(bmax, sw1, sb1, sw2, sb2, sw3, sb3, filt);
        float* apOut = apBuf[lev & 1];
        wconv_k<<<4096, 256, 0, stream>>>(apIn, filt, apOut, stacked, lev);
        apIn = apOut;
    }
    copy4_k<<<4096, 256, 0, stream>>>(stacked, y);

    dim3 cg(64, 8);
    auto stage = [&](int tix, const Combo6& cin, float* outS, bool yup) {
        conv1_k<<<cg, 256, 0, stream>>>(cin, wp1, kb1, cond, tix, h1);
        conv2_k<<<cg, 256, 0, stream>>>(h1, wp2, kb2, h2);
        if (yup)
            conv3_k<true><<<cg, 256, 0, stream>>>(h2, wp3, kb3, nullptr, y, s1, s3, s4, s5);
        else
            conv3_k<false><<<cg, 256, 0, stream>>>(h2, wp3, kb3, outS, nullptr, nullptr, nullptr, nullptr, nullptr);
    };

    const float hs = HS;
    for (int i = 0; i < 4; ++i) {
        Combo6 cA{}; cA.p[0] = y; cA.n = 1;
        stage(i*6+0, cA, s1, false);

        Combo6 cB{}; cB.p[0] = y; cB.p[1] = s1; cB.c[1] = hs*(1.f/5.f); cB.n = 2;
        stage(i*6+1, cB, s2, false);

        Combo6 cC{}; cC.p[0] = y;
        cC.p[1] = s1; cC.c[1] = hs*(3.f/40.f);
        cC.p[2] = s2; cC.c[2] = hs*(9.f/40.f); cC.n = 3;
        stage(i*6+2, cC, s3, false);

        Combo6 cD{}; cD.p[0] = y;
        cD.p[1] = s1; cD.c[1] = hs*(44.f/45.f);
        cD.p[2] = s2; cD.c[2] = -hs*(56.f/15.f);
        cD.p[3] = s3; cD.c[3] = hs*(32.f/9.f); cD.n = 4;
        stage(i*6+3, cD, s4, false);

        Combo6 cE{}; cE.p[0] = y;
        cE.p[1] = s1; cE.c[1] = hs*(19372.f/6561.f);
        cE.p[2] = s2; cE.c[2] = -hs*(25360.f/2187.f);
        cE.p[3] = s3; cE.c[3] = hs*(64448.f/6561.f);
        cE.p[4] = s4; cE.c[4] = -hs*(212.f/729.f); cE.n = 5;
        stage(i*6+4, cE, s5, false);

        Combo6 cF{}; cF.p[0] = y;
        cF.p[1] = s1; cF.c[1] = hs*(9017.f/3168.f);
        cF.p[2] = s2; cF.c[2] = -hs*(355.f/33.f);
        cF.p[3] = s3; cF.c[3] = hs*(46732.f/5247.f);
        cF.p[4] = s4; cF.c[4] = hs*(49.f/176.f);
        cF.p[5] = s5; cF.c[5] = -hs*(5103.f/18656.f); cF.n = 6;
        stage(i*6+5, cF, nullptr, true);   // s6 -> fused y update, never stored
    }

    // dx = ode_f(1.0, y) -> s1; ecloss; outputs
    Combo6 cZ{}; cZ.p[0] = y; cZ.n = 1;
    stage(24, cZ, s1, false);
    ecred_k<<<1024, 256, 0, stream>>>(stacked, s1, inner);
    ecfin_k<<<1, 1, 0, stream>>>(inner, out);
    gather_k<<<4096, 256, 0, stream>>>(y, out);
}

// Round 3
// 1308.511 us; speedup vs baseline: 5.4620x; 5.4620x over previous
//
#include <hip/hip_runtime.h>
#include <math.h>

#define B 8
#define C 64
#define L 2048
#define CS 256
#define BCL  (B*C*L)    // 1048576
#define BCSL (B*CS*L)   // 4194304
#define HS 0.25f

typedef unsigned short u16;
typedef unsigned int   u32;
typedef __attribute__((ext_vector_type(8))) short sh8;
typedef __attribute__((ext_vector_type(4))) float f4;

__device__ __forceinline__ float gelu(float x) {
    return 0.5f * x * (1.0f + erff(x * 0.70710678118654752440f));
}
__device__ __forceinline__ u16 f2b(float f) {
    u32 u = __float_as_uint(f);
    u32 r = u + 0x7FFFu + ((u >> 16) & 1u);
    return (u16)(r >> 16);
}

struct Combo6 { const float* p[6]; float c[6]; };

// ---------- weight prep: fp32 [oc][ic][k] -> bf16 A-frag order ----------
// K = kk*IC + ic (k-major). dst idx: [chunk][ocg][lane][j]
__global__ __launch_bounds__(256) void prep_k(const float* __restrict__ w,
        u16* __restrict__ dst, int IC, int OC) {
    int idx = blockIdx.x * 256 + threadIdx.x;
    int OCG = OC >> 4;
    int j = idx & 7, lane = (idx >> 3) & 63, t = idx >> 9;
    int ocg = t % OCG, c = t / OCG;
    int oc = ocg * 16 + (lane & 15);
    int K = c * 32 + ((lane >> 4) & 3) * 8 + j;
    int kk = K / IC, ic = K % IC;
    dst[idx] = f2b(w[((size_t)oc * IC + ic) * 3 + kk]);
}

// ---------- all 25 cond vectors ----------
__global__ void cond25_k(const float* __restrict__ tw1, const float* __restrict__ tb1,
                         const float* __restrict__ tw2, const float* __restrict__ tb2,
                         const float* __restrict__ cw, const float* __restrict__ cb,
                         float* __restrict__ condall) {
    __shared__ float te1[16], te2[16];
    int tix = blockIdx.x;
    int tid = threadIdx.x;
    double add[6] = {0.0, 0.25/5.0, 3.0*0.25/10.0, 4.0*0.25/5.0, 8.0*0.25/9.0, 0.25};
    float t = (tix == 24) ? 1.0f : (float)((double)(tix / 6) * 0.25 + add[tix % 6]);
    if (tid < 16) te1[tid] = gelu(t * tw1[tid] + tb1[tid]);
    __syncthreads();
    if (tid < 16) {
        float s = tb2[tid];
        for (int k = 0; k < 16; ++k) s += te1[k] * tw2[tid*16+k];
        te2[tid] = s;
    }
    __syncthreads();
    float s = cb[tid];
    for (int j = 0; j < 16; ++j) s += te2[j] * cw[tid*16+j];
    condall[tix*128 + tid] = s;
}

// ---------- fused ode_f: conv1(FiLM,GELU) -> conv2(GELU) -> conv3 ----------
// grid (64,8), block 256. Final tile: 32 positions, all 256 oc.
// Halo chain: conv1 in 38 pos (g0=l0-3) -> conv1 out 36 -> conv2 out 34 -> conv3 out 32.
// EPI: 0 = store outS; 1 = fused y-update; 2 = y-update + permuted out; 3 = ecloss
template<int NC, int EPI>
__global__ __launch_bounds__(256) void fused_k(Combo6 in,
        const u16* __restrict__ wp1, const float* __restrict__ kb1,
        const u16* __restrict__ wp2, const float* __restrict__ kb2,
        const u16* __restrict__ wp3, const float* __restrict__ kb3,
        const float* __restrict__ condall, int tix,
        float* __restrict__ outS,
        float* __restrict__ y, const float* __restrict__ s1,
        const float* __restrict__ s3, const float* __restrict__ s4,
        const float* __restrict__ s5,
        float* __restrict__ outp, const float* __restrict__ stacked,
        double* __restrict__ inner)
{
    __shared__ u16 xs1[50][264];   // [pos][ic] conv1 input (bf16)
    __shared__ u16 h1t[50][72];    // [pos][oc] conv1 output
    __shared__ u16 h2t[48][72];    // [pos][oc] conv2 output
    __shared__ double sred[4];
    const int tid = threadIdx.x;
    const int l0  = blockIdx.x * 32;
    const int b   = blockIdx.y;
    const int g0  = l0 - 3;

    // zero never-written-but-read rows
    for (int i = tid; i < 12*264; i += 256) xs1[38 + i/264][i%264] = 0;
    if (tid < 144) h1t[48 + tid/72][tid%72] = 0;

    // stage combo -> bf16 transposed LDS (coalesced: r fast-varying)
    for (int idx = tid; idx < 256*38; idx += 256) {
        int ic = idx / 38, r = idx - ic*38;
        int gl = g0 + r;
        float v = 0.f;
        if (gl >= 0 && gl < L) {
            size_t a = ((size_t)b*CS + ic)*L + gl;
            v = in.p[0][a];
            #pragma unroll
            for (int t = 1; t < NC; ++t) v += in.c[t] * in.p[t][a];
        }
        xs1[r][ic] = f2b(v);
    }
    __syncthreads();

    const int wave = tid >> 6, lane = tid & 63;
    const int nlo = lane & 15, quad = lane >> 4;

    // ---- conv1: M=16/wave, N=48, K=768 ----
    f4 a1[3];
    a1[0] = f4{0.f,0.f,0.f,0.f}; a1[1] = a1[0]; a1[2] = a1[0];
    {
        const sh8* w1 = (const sh8*)wp1;
        for (int c = 0; c < 24; ++c) {
            int kk = c >> 3, ic0 = (c & 7) << 5;
            sh8 A = w1[(c*4 + wave)*64 + lane];
            #pragma unroll
            for (int nf = 0; nf < 3; ++nf) {
                sh8 Bv = *(const sh8*)&xs1[nf*16 + nlo + kk][ic0 + quad*8];
                a1[nf] = __builtin_amdgcn_mfma_f32_16x16x32_bf16(A, Bv, a1[nf], 0, 0, 0);
            }
        }
    }
    {
        const float* cd = condall + tix*128;
        #pragma unroll
        for (int nf = 0; nf < 3; ++nf) {
            int p = nf*16 + nlo;
            int gp = l0 - 2 + p;                    // global pos of h1 row p
            bool ok = (gp >= 0 && gp < L);          // zero-pad semantics
            #pragma unroll
            for (int reg = 0; reg < 4; ++reg) {
                int oc = wave*16 + quad*4 + reg;
                float v = (1.f + cd[oc]) * (a1[nf][reg] + kb1[oc]) + cd[64+oc];
                h1t[p][oc] = ok ? f2b(gelu(v)) : (u16)0;
            }
        }
    }
    __syncthreads();

    // ---- conv2: M=16/wave, N=48, K=192 ----
    f4 a2[3];
    a2[0] = f4{0.f,0.f,0.f,0.f}; a2[1] = a2[0]; a2[2] = a2[0];
    {
        const sh8* w2 = (const sh8*)wp2;
        #pragma unroll
        for (int c = 0; c < 6; ++c) {
            int kk = c >> 1, ic0 = (c & 1) << 5;
            sh8 A = w2[(c*4 + wave)*64 + lane];
            #pragma unroll
            for (int nf = 0; nf < 3; ++nf) {
                sh8 Bv = *(const sh8*)&h1t[nf*16 + nlo + kk][ic0 + quad*8];
                a2[nf] = __builtin_amdgcn_mfma_f32_16x16x32_bf16(A, Bv, a2[nf], 0, 0, 0);
            }
        }
    }
    {
        #pragma unroll
        for (int nf = 0; nf < 3; ++nf) {
            int q = nf*16 + nlo;
            int gq = l0 - 1 + q;                    // global pos of h2 row q
            bool ok = (gq >= 0 && gq < L);
            #pragma unroll
            for (int reg = 0; reg < 4; ++reg) {
                int oc = wave*16 + quad*4 + reg;
                h2t[q][oc] = ok ? f2b(gelu(a2[nf][reg] + kb2[oc])) : (u16)0;
            }
        }
    }
    __syncthreads();

    // ---- conv3: M=64/wave, N=32, K=192 ----
    f4 a3[4][2];
    #pragma unroll
    for (int mf = 0; mf < 4; ++mf) {
        a3[mf][0] = f4{0.f,0.f,0.f,0.f}; a3[mf][1] = a3[mf][0];
    }
    {
        const sh8* w3 = (const sh8*)wp3;
        #pragma unroll
        for (int c = 0; c < 6; ++c) {
            int kk = c >> 1, ic0 = (c & 1) << 5;
            sh8 B0 = *(const sh8*)&h2t[nlo + kk][ic0 + quad*8];
            sh8 B1 = *(const sh8*)&h2t[16 + nlo + kk][ic0 + quad*8];
            #pragma unroll
            for (int mf = 0; mf < 4; ++mf) {
                sh8 A = w3[(c*16 + wave*4 + mf)*64 + lane];
                a3[mf][0] = __builtin_amdgcn_mfma_f32_16x16x32_bf16(A, B0, a3[mf][0], 0, 0, 0);
                a3[mf][1] = __builtin_amdgcn_mfma_f32_16x16x32_bf16(A, B1, a3[mf][1], 0, 0, 0);
            }
        }
    }

    // ---- epilogue ----
    if (EPI == 3) {
        double acc = 0.0;
        #pragma unroll
        for (int mf = 0; mf < 4; ++mf)
            #pragma unroll
            for (int nf = 0; nf < 2; ++nf)
                #pragma unroll
                for (int reg = 0; reg < 4; ++reg) {
                    int oc = (wave*4 + mf)*16 + quad*4 + reg;
                    int pos = l0 + nf*16 + nlo;
                    size_t idx = ((size_t)b*CS + oc)*L + pos;
                    float dx = a3[mf][nf][reg] + kb3[oc];
                    acc += (double)stacked[idx] * (double)dx;
                }
        #pragma unroll
        for (int off = 32; off > 0; off >>= 1) acc += __shfl_down(acc, off, 64);
        if (lane == 0) sred[wave] = acc;
        __syncthreads();
        if (tid == 0) atomicAdd(&inner[b], sred[0] + sred[1] + sred[2] + sred[3]);
    } else {
        const float c1 = HS*(35.f/384.f), c3 = HS*(500.f/1113.f),
                    c4 = HS*(125.f/192.f), c5 = -HS*(2187.f/6784.f),
                    c6 = HS*(11.f/84.f);
        #pragma unroll
        for (int mf = 0; mf < 4; ++mf) {
            #pragma unroll
            for (int nf = 0; nf < 2; ++nf) {
                #pragma unroll
                for (int reg = 0; reg < 4; ++reg) {
                    int oc = (wave*4 + mf)*16 + quad*4 + reg;
                    int pos = l0 + nf*16 + nlo;
                    size_t idx = ((size_t)b*CS + oc)*L + pos;
                    float v = a3[mf][nf][reg] + kb3[oc];
                    if (EPI == 0) {
                        outS[idx] = v;
                    } else {
                        float yv = y[idx] + c1*s1[idx] + c3*s3[idx] + c4*s4[idx]
                                 + c5*s5[idx] + c6*v;
                        y[idx] = yv;
                        if (EPI == 2) {
                            size_t oidx = (((size_t)(oc >> 6)*B + b)*64 + (oc & 63))*L + pos;
                            outp[oidx] = yv;
                        }
                    }
                }
            }
        }
    }
}

// ---------- wavelet part ----------
__global__ __launch_bounds__(256) void rowmax_k(const float* __restrict__ a, float* __restrict__ bm) {
    __shared__ float red[256];
    int row = blockIdx.x;
    const float* p = a + (size_t)row * L;
    float m = -1e30f;
    for (int t = threadIdx.x; t < L; t += 256) m = fmaxf(m, p[t]);
    red[threadIdx.x] = m;
    __syncthreads();
    for (int s = 128; s > 0; s >>= 1) {
        if (threadIdx.x < s) red[threadIdx.x] = fmaxf(red[threadIdx.x], red[threadIdx.x + s]);
        __syncthreads();
    }
    if (threadIdx.x == 0) bm[row] = red[0];
}

__global__ __launch_bounds__(256) void mlp_k(const float* __restrict__ bm,
    const float* __restrict__ sw1, const float* __restrict__ sb1,
    const float* __restrict__ sw2, const float* __restrict__ sb2,
    const float* __restrict__ sw3, const float* __restrict__ sb3,
    float* __restrict__ filt) {
    __shared__ float m[8][64], f1[8][32], f2[8][32], raw[8][16], nrm[8][2];
    int tid = threadIdx.x;
    for (int i = tid; i < 512; i += 256) m[i >> 6][i & 63] = bm[i];
    __syncthreads();
    {
        int b = tid >> 5, h = tid & 31;
        float s = sb1[h];
        for (int c = 0; c < 64; ++c) s += m[b][c] * sw1[h*64+c];
        f1[b][h] = gelu(s);
    }
    __syncthreads();
    {
        int b = tid >> 5, h = tid & 31;
        float s = sb2[h];
        for (int k = 0; k < 32; ++k) s += f1[b][k] * sw2[h*32+k];
        f2[b][h] = gelu(s);
    }
    __syncthreads();
    if (tid < 128) {
        int b = tid >> 4, j = tid & 15;
        float s = sb3[j];
        for (int k = 0; k < 32; ++k) s += f2[b][k] * sw3[j*32+k];
        raw[b][j] = s;
    }
    __syncthreads();
    if (tid < 16) {
        int b = tid >> 1, half = tid & 1;
        float s = 0.f;
        for (int j = 0; j < 8; ++j) { float v = raw[b][half*8+j]; s += v*v; }
        nrm[b][half] = sqrtf(s);
    }
    __syncthreads();
    if (tid < 16) {
        int half = tid >> 3;
        float s = 0.f;
        for (int b = 0; b < 8; ++b) s += raw[b][tid] / nrm[b][half];
        filt[tid] = s * 0.125f;
    }
}

__global__ __launch_bounds__(256) void wconv_k(const float* __restrict__ ap,
    const float* __restrict__ filt, float* __restrict__ apOut,
    float* __restrict__ stacked, int lev) {
    __shared__ float f[16];
    if (threadIdx.x < 16) f[threadIdx.x] = filt[threadIdx.x];
    __syncthreads();
    size_t idx = (size_t)blockIdx.x * 256 + threadIdx.x;
    int l = (int)(idx & 2047);
    size_t bc = idx >> 11;
    int c = (int)(bc & 63), b = (int)(bc >> 6);
    const float* row = ap + (bc << 11);
    float lo = 0.f, hi = 0.f;
    #pragma unroll
    for (int k = 0; k < 8; ++k) {
        int mI = l + k - 3;
        mI = mI < 0 ? -mI : (mI >= L ? 2*L - 2 - mI : mI);
        float v = row[mI];
        lo += v * f[k];
        hi += v * f[8+k];
    }
    apOut[idx] = lo;
    stacked[((size_t)b * CS + (size_t)(lev+1) * 64 + c) * L + l] = hi;
}

__global__ __launch_bounds__(256) void copyx_k(const float* __restrict__ x, float* __restrict__ st) {
    size_t i = (size_t)blockIdx.x * 256 + threadIdx.x;
    size_t b = i >> 17, rem = i & 131071;
    st[b * ((size_t)CS*L) + rem] = x[i];
}

__global__ __launch_bounds__(256) void copy4_k(const float* __restrict__ s, float* __restrict__ d) {
    size_t i = (size_t)blockIdx.x * 256 + threadIdx.x;
    ((float4*)d)[i] = ((const float4*)s)[i];
}

__global__ void ecfin_k(const double* __restrict__ inner, float* __restrict__ out) {
    double s = 0.0;
    for (int b = 0; b < 8; ++b) s += inner[b] * inner[b];
    out[BCSL] = (float)(s / 8.0);
}

extern "C" void kernel_launch(void* const* d_in, const int* in_sizes, int n_in,
                              void* d_out, int out_size, void* d_ws, size_t ws_size,
                              hipStream_t stream) {
    const float* x   = (const float*)d_in[0];
    const float* sw1 = (const float*)d_in[1];
    const float* sb1 = (const float*)d_in[2];
    const float* sw2 = (const float*)d_in[3];
    const float* sb2 = (const float*)d_in[4];
    const float* sw3 = (const float*)d_in[5];
    const float* sb3 = (const float*)d_in[6];
    const float* tw1 = (const float*)d_in[7];
    const float* tb1 = (const float*)d_in[8];
    const float* tw2 = (const float*)d_in[9];
    const float* tb2 = (const float*)d_in[10];
    const float* cw  = (const float*)d_in[11];
    const float* cb  = (const float*)d_in[12];
    const float* k1  = (const float*)d_in[13];
    const float* kb1 = (const float*)d_in[14];
    const float* k2  = (const float*)d_in[15];
    const float* kb2 = (const float*)d_in[16];
    const float* k3  = (const float*)d_in[17];
    const float* kb3 = (const float*)d_in[18];
    float* out = (float*)d_out;

    float* ws = (float*)d_ws;
    float* stacked = ws;                 // BCSL
    float* y    = stacked + BCSL;
    float* s1   = y  + BCSL;
    float* s2   = s1 + BCSL;
    float* s3   = s2 + BCSL;
    float* s4   = s3 + BCSL;
    float* s5   = s4 + BCSL;
    float* cond = s5 + BCSL;             // 3200
    float* bmax = cond + 3200;           // 512
    float* filt = bmax + 512;            // 16
    double* inner = (double*)(filt + 16);            // 8 doubles
    u16* wp1 = (u16*)(filt + 32);                    // 49152
    u16* wp2 = wp1 + 49152;                          // 12288
    u16* wp3 = wp2 + 12288;                          // 49152

    hipMemsetAsync(inner, 0, 8 * sizeof(double), stream);

    prep_k<<<192, 256, 0, stream>>>(k1, wp1, CS, C);
    prep_k<<<48,  256, 0, stream>>>(k2, wp2, C,  C);
    prep_k<<<192, 256, 0, stream>>>(k3, wp3, C,  CS);
    cond25_k<<<25, 128, 0, stream>>>(tw1, tb1, tw2, tb2, cw, cb, cond);

    // wavelet decomposition (s2/s3 fp32 scratch, free before ODE)
    copyx_k<<<4096, 256, 0, stream>>>(x, stacked);
    const float* apIn = x;
    float* apBuf[2] = {s2, s3};
    for (int lev = 0; lev < 3; ++lev) {
        rowmax_k<<<512, 256, 0, stream>>>(apIn, bmax);
        mlp_k<<<1, 256, 0, stream>>>(bmax, sw1, sb1, sw2, sb2, sw3, sb3, filt);
        float* apOut = apBuf[lev & 1];
        wconv_k<<<4096, 256, 0, stream>>>(apIn, filt, apOut, stacked, lev);
        apIn = apOut;
    }
    copy4_k<<<4096, 256, 0, stream>>>(stacked, y);

    const float hs = HS;
    dim3 cg(64, 8);
    #define LAUNCH(NC, EPI, CIN, TIX, OUTS, OUTP, STK) \
        fused_k<NC, EPI><<<cg, 256, 0, stream>>>(CIN, wp1, kb1, wp2, kb2, wp3, kb3, \
            cond, TIX, OUTS, y, s1, s3, s4, s5, OUTP, STK, inner)

    for (int i = 0; i < 4; ++i) {
        Combo6 cA{}; cA.p[0] = y;
        LAUNCH(1, 0, cA, i*6+0, s1, nullptr, nullptr);

        Combo6 cB{}; cB.p[0] = y; cB.p[1] = s1; cB.c[1] = hs*(1.f/5.f);
        LAUNCH(2, 0, cB, i*6+1, s2, nullptr, nullptr);

        Combo6 cC{}; cC.p[0] = y;
        cC.p[1] = s1; cC.c[1] = hs*(3.f/40.f);
        cC.p[2] = s2; cC.c[2] = hs*(9.f/40.f);
        LAUNCH(3, 0, cC, i*6+2, s3, nullptr, nullptr);

        Combo6 cD{}; cD.p[0] = y;
        cD.p[1] = s1; cD.c[1] = hs*(44.f/45.f);
        cD.p[2] = s2; cD.c[2] = -hs*(56.f/15.f);
        cD.p[3] = s3; cD.c[3] = hs*(32.f/9.f);
        LAUNCH(4, 0, cD, i*6+3, s4, nullptr, nullptr);

        Combo6 cE{}; cE.p[0] = y;
        cE.p[1] = s1; cE.c[1] = hs*(19372.f/6561.f);
        cE.p[2] = s2; cE.c[2] = -hs*(25360.f/2187.f);
        cE.p[3] = s3; cE.c[3] = hs*(64448.f/6561.f);
        cE.p[4] = s4; cE.c[4] = -hs*(212.f/729.f);
        LAUNCH(5, 0, cE, i*6+4, s5, nullptr, nullptr);

        Combo6 cF{}; cF.p[0] = y;
        cF.p[1] = s1; cF.c[1] = hs*(9017.f/3168.f);
        cF.p[2] = s2; cF.c[2] = -hs*(355.f/33.f);
        cF.p[3] = s3; cF.c[3] = hs*(46732.f/5247.f);
        cF.p[4] = s4; cF.c[4] = hs*(49.f/176.f);
        cF.p[5] = s5; cF.c[5] = -hs*(5103.f/18656.f);
        if (i < 3) {
            LAUNCH(6, 1, cF, i*6+5, nullptr, nullptr, nullptr);   // y update
        } else {
            LAUNCH(6, 2, cF, i*6+5, nullptr, out, nullptr);       // y update + gather
        }
    }

    // dx = ode_f(1.0, y), ecloss fused (dx never stored)
    Combo6 cZ{}; cZ.p[0] = y;
    LAUNCH(1, 3, cZ, 24, nullptr, nullptr, stacked);
    ecfin_k<<<1, 1, 0, stream>>>(inner, out);
    #undef LAUNCH
}

// Round 4
// 775.454 us; speedup vs baseline: 9.2167x; 1.6874x over previous
//
#include <hip/hip_runtime.h>
#include <math.h>

#define B 8
#define C 64
#define L 2048
#define CS 256
#define BCL  (B*C*L)    // 1048576
#define BCSL (B*CS*L)   // 4194304
#define HS 0.25f

typedef unsigned short u16;
typedef unsigned int   u32;
typedef __attribute__((ext_vector_type(8))) short sh8;
typedef __attribute__((ext_vector_type(4))) float f4;
typedef __attribute__((ext_vector_type(8))) unsigned short us8;
typedef __attribute__((ext_vector_type(4))) unsigned short us4;

__device__ __forceinline__ float gelu(float x) {
    return 0.5f * x * (1.0f + erff(x * 0.70710678118654752440f));
}
__device__ __forceinline__ u16 f2b(float f) {
    u32 u = __float_as_uint(f);
    u32 r = u + 0x7FFFu + ((u >> 16) & 1u);
    return (u16)(r >> 16);
}
__device__ __forceinline__ float b2f(u16 h) {
    return __uint_as_float(((u32)h) << 16);
}

struct ComboB { const u16* p[6]; float c[6]; };

// ---------- weight prep: fp32 [oc][ic][k] -> bf16 A-frag order ----------
__global__ __launch_bounds__(256) void prep_k(const float* __restrict__ w,
        u16* __restrict__ dst, int IC, int OC) {
    int idx = blockIdx.x * 256 + threadIdx.x;
    int OCG = OC >> 4;
    int j = idx & 7, lane = (idx >> 3) & 63, t = idx >> 9;
    int ocg = t % OCG, c = t / OCG;
    int oc = ocg * 16 + (lane & 15);
    int K = c * 32 + ((lane >> 4) & 3) * 8 + j;
    int kk = K / IC, ic = K % IC;
    dst[idx] = f2b(w[((size_t)oc * IC + ic) * 3 + kk]);
}

// ---------- all 25 cond vectors ----------
__global__ void cond25_k(const float* __restrict__ tw1, const float* __restrict__ tb1,
                         const float* __restrict__ tw2, const float* __restrict__ tb2,
                         const float* __restrict__ cw, const float* __restrict__ cb,
                         float* __restrict__ condall) {
    __shared__ float te1[16], te2[16];
    int tix = blockIdx.x;
    int tid = threadIdx.x;
    double add[6] = {0.0, 0.25/5.0, 3.0*0.25/10.0, 4.0*0.25/5.0, 8.0*0.25/9.0, 0.25};
    float t = (tix == 24) ? 1.0f : (float)((double)(tix / 6) * 0.25 + add[tix % 6]);
    if (tid < 16) te1[tid] = gelu(t * tw1[tid] + tb1[tid]);
    __syncthreads();
    if (tid < 16) {
        float s = tb2[tid];
        for (int k = 0; k < 16; ++k) s += te1[k] * tw2[tid*16+k];
        te2[tid] = s;
    }
    __syncthreads();
    float s = cb[tid];
    for (int j = 0; j < 16; ++j) s += te2[j] * cw[tid*16+j];
    condall[tix*128 + tid] = s;
}

// ---------- fused ode_f: conv1(FiLM,GELU) -> conv2(GELU) -> conv3 ----------
// All conv inputs (yb, s*) are bf16 in TRANSPOSED layout [b][pos][ch].
// y stays fp32 [b][c][l], touched only in the RK epilogue.
// EPI: 0 = store s (bf16 transposed); 1 = y update (+yb); 2 = y update + permuted out (+yb, no y store); 3 = ecloss
template<int NC, int EPI>
__global__ __launch_bounds__(256) void fused_k(ComboB in,
        const u16* __restrict__ wp1, const float* __restrict__ kb1,
        const u16* __restrict__ wp2, const float* __restrict__ kb2,
        const u16* __restrict__ wp3, const float* __restrict__ kb3,
        const float* __restrict__ condall, int tix,
        u16* __restrict__ outSb,
        float* __restrict__ y, u16* __restrict__ yb,
        const u16* __restrict__ s1b, const u16* __restrict__ s3b,
        const u16* __restrict__ s4b, const u16* __restrict__ s5b,
        float* __restrict__ outp, const float* __restrict__ stacked,
        double* __restrict__ inner)
{
    __shared__ u16 xs1[50][264];   // [pos][ic] conv1 input (bf16)
    __shared__ u16 h1t[50][72];    // [pos][oc] conv1 output
    __shared__ u16 h2t[48][72];    // [pos][oc] conv2 output
    __shared__ double sred[4];
    const int tid = threadIdx.x;
    const int l0  = blockIdx.x * 32;
    const int b   = blockIdx.y;
    const int g0  = l0 - 3;

    // zero never-written-but-read rows
    for (int i = tid; i < 12*264; i += 256) xs1[38 + i/264][i%264] = 0;
    if (tid < 144) h1t[48 + tid/72][tid%72] = 0;

    // stage combo (bf16 transposed in) -> bf16 transposed LDS; fully coalesced
    for (int idx = tid; idx < 38*32; idx += 256) {
        int r = idx >> 5, c8 = idx & 31;
        int gl = g0 + r;
        us8 val;
        if (gl >= 0 && gl < L) {
            size_t a = ((size_t)b * L + gl) * 256 + c8 * 8;
            us8 v0 = *(const us8*)(in.p[0] + a);
            if (NC == 1) {
                val = v0;
            } else {
                float f[8];
                #pragma unroll
                for (int j = 0; j < 8; ++j) f[j] = b2f(v0[j]);
                #pragma unroll
                for (int t = 1; t < NC; ++t) {
                    us8 vt = *(const us8*)(in.p[t] + a);
                    #pragma unroll
                    for (int j = 0; j < 8; ++j) f[j] += in.c[t] * b2f(vt[j]);
                }
                #pragma unroll
                for (int j = 0; j < 8; ++j) val[j] = f2b(f[j]);
            }
        } else {
            #pragma unroll
            for (int j = 0; j < 8; ++j) val[j] = 0;
        }
        *(us8*)&xs1[r][c8 * 8] = val;
    }
    __syncthreads();

    const int wave = tid >> 6, lane = tid & 63;
    const int nlo = lane & 15, quad = lane >> 4;

    // ---- conv1: M=16/wave, N=48, K=768 ----
    f4 a1[3];
    a1[0] = f4{0.f,0.f,0.f,0.f}; a1[1] = a1[0]; a1[2] = a1[0];
    {
        const sh8* w1 = (const sh8*)wp1;
        for (int c = 0; c < 24; ++c) {
            int kk = c >> 3, ic0 = (c & 7) << 5;
            sh8 A = w1[(c*4 + wave)*64 + lane];
            #pragma unroll
            for (int nf = 0; nf < 3; ++nf) {
                sh8 Bv = *(const sh8*)&xs1[nf*16 + nlo + kk][ic0 + quad*8];
                a1[nf] = __builtin_amdgcn_mfma_f32_16x16x32_bf16(A, Bv, a1[nf], 0, 0, 0);
            }
        }
    }
    {
        const float* cd = condall + tix*128;
        #pragma unroll
        for (int nf = 0; nf < 3; ++nf) {
            int p = nf*16 + nlo;
            int gp = l0 - 2 + p;
            bool ok = (gp >= 0 && gp < L);
            #pragma unroll
            for (int reg = 0; reg < 4; ++reg) {
                int oc = wave*16 + quad*4 + reg;
                float v = (1.f + cd[oc]) * (a1[nf][reg] + kb1[oc]) + cd[64+oc];
                h1t[p][oc] = ok ? f2b(gelu(v)) : (u16)0;
            }
        }
    }
    __syncthreads();

    // ---- conv2: M=16/wave, N=48, K=192 ----
    f4 a2[3];
    a2[0] = f4{0.f,0.f,0.f,0.f}; a2[1] = a2[0]; a2[2] = a2[0];
    {
        const sh8* w2 = (const sh8*)wp2;
        #pragma unroll
        for (int c = 0; c < 6; ++c) {
            int kk = c >> 1, ic0 = (c & 1) << 5;
            sh8 A = w2[(c*4 + wave)*64 + lane];
            #pragma unroll
            for (int nf = 0; nf < 3; ++nf) {
                sh8 Bv = *(const sh8*)&h1t[nf*16 + nlo + kk][ic0 + quad*8];
                a2[nf] = __builtin_amdgcn_mfma_f32_16x16x32_bf16(A, Bv, a2[nf], 0, 0, 0);
            }
        }
    }
    {
        #pragma unroll
        for (int nf = 0; nf < 3; ++nf) {
            int q = nf*16 + nlo;
            int gq = l0 - 1 + q;
            bool ok = (gq >= 0 && gq < L);
            #pragma unroll
            for (int reg = 0; reg < 4; ++reg) {
                int oc = wave*16 + quad*4 + reg;
                h2t[q][oc] = ok ? f2b(gelu(a2[nf][reg] + kb2[oc])) : (u16)0;
            }
        }
    }
    __syncthreads();

    // ---- conv3: M=64/wave, N=32, K=192 ----
    f4 a3[4][2];
    #pragma unroll
    for (int mf = 0; mf < 4; ++mf) {
        a3[mf][0] = f4{0.f,0.f,0.f,0.f}; a3[mf][1] = a3[mf][0];
    }
    {
        const sh8* w3 = (const sh8*)wp3;
        #pragma unroll
        for (int c = 0; c < 6; ++c) {
            int kk = c >> 1, ic0 = (c & 1) << 5;
            sh8 B0 = *(const sh8*)&h2t[nlo + kk][ic0 + quad*8];
            sh8 B1 = *(const sh8*)&h2t[16 + nlo + kk][ic0 + quad*8];
            #pragma unroll
            for (int mf = 0; mf < 4; ++mf) {
                sh8 A = w3[(c*16 + wave*4 + mf)*64 + lane];
                a3[mf][0] = __builtin_amdgcn_mfma_f32_16x16x32_bf16(A, B0, a3[mf][0], 0, 0, 0);
                a3[mf][1] = __builtin_amdgcn_mfma_f32_16x16x32_bf16(A, B1, a3[mf][1], 0, 0, 0);
            }
        }
    }

    // ---- epilogue ----
    if (EPI == 3) {
        double acc = 0.0;
        #pragma unroll
        for (int mf = 0; mf < 4; ++mf)
            #pragma unroll
            for (int nf = 0; nf < 2; ++nf)
                #pragma unroll
                for (int reg = 0; reg < 4; ++reg) {
                    int oc = (wave*4 + mf)*16 + quad*4 + reg;
                    int pos = l0 + nf*16 + nlo;
                    size_t idx = ((size_t)b*CS + oc)*L + pos;
                    float dx = a3[mf][nf][reg] + kb3[oc];
                    acc += (double)stacked[idx] * (double)dx;
                }
        #pragma unroll
        for (int off = 32; off > 0; off >>= 1) acc += __shfl_down(acc, off, 64);
        if (lane == 0) sred[wave] = acc;
        __syncthreads();
        if (tid == 0) atomicAdd(&inner[b], sred[0] + sred[1] + sred[2] + sred[3]);
    } else if (EPI == 0) {
        #pragma unroll
        for (int mf = 0; mf < 4; ++mf) {
            int baseoc = (wave*4 + mf)*16 + quad*4;
            #pragma unroll
            for (int nf = 0; nf < 2; ++nf) {
                int pos = l0 + nf*16 + nlo;
                us4 pk;
                #pragma unroll
                for (int reg = 0; reg < 4; ++reg)
                    pk[reg] = f2b(a3[mf][nf][reg] + kb3[baseoc + reg]);
                *(us4*)(outSb + ((size_t)b*L + pos)*256 + baseoc) = pk;
            }
        }
    } else {
        const float c1 = HS*(35.f/384.f), c3 = HS*(500.f/1113.f),
                    c4 = HS*(125.f/192.f), c5 = -HS*(2187.f/6784.f),
                    c6 = HS*(11.f/84.f);
        #pragma unroll
        for (int mf = 0; mf < 4; ++mf) {
            int baseoc = (wave*4 + mf)*16 + quad*4;
            #pragma unroll
            for (int nf = 0; nf < 2; ++nf) {
                int pos = l0 + nf*16 + nlo;
                size_t ta = ((size_t)b*L + pos)*256 + baseoc;
                us4 v1 = *(const us4*)(s1b + ta);
                us4 v3 = *(const us4*)(s3b + ta);
                us4 v4 = *(const us4*)(s4b + ta);
                us4 v5 = *(const us4*)(s5b + ta);
                us4 pk;
                #pragma unroll
                for (int reg = 0; reg < 4; ++reg) {
                    int oc = baseoc + reg;
                    size_t idx = ((size_t)b*CS + oc)*L + pos;
                    float s6 = a3[mf][nf][reg] + kb3[oc];
                    float yv = y[idx] + c1*b2f(v1[reg]) + c3*b2f(v3[reg])
                             + c4*b2f(v4[reg]) + c5*b2f(v5[reg]) + c6*s6;
                    pk[reg] = f2b(yv);
                    if (EPI == 1) y[idx] = yv;
                    if (EPI == 2) {
                        size_t oidx = (((size_t)(oc >> 6)*B + b)*64 + (oc & 63))*L + pos;
                        outp[oidx] = yv;
                    }
                }
                *(us4*)(yb + ta) = pk;
            }
        }
    }
}

// ---------- wavelet part ----------
__global__ __launch_bounds__(256) void rowmax_k(const float* __restrict__ a, float* __restrict__ bm) {
    __shared__ float red[256];
    int row = blockIdx.x;
    const float* p = a + (size_t)row * L;
    float m = -1e30f;
    for (int t = threadIdx.x; t < L; t += 256) m = fmaxf(m, p[t]);
    red[threadIdx.x] = m;
    __syncthreads();
    for (int s = 128; s > 0; s >>= 1) {
        if (threadIdx.x < s) red[threadIdx.x] = fmaxf(red[threadIdx.x], red[threadIdx.x + s]);
        __syncthreads();
    }
    if (threadIdx.x == 0) bm[row] = red[0];
}

__global__ __launch_bounds__(256) void mlp_k(const float* __restrict__ bm,
    const float* __restrict__ sw1, const float* __restrict__ sb1,
    const float* __restrict__ sw2, const float* __restrict__ sb2,
    const float* __restrict__ sw3, const float* __restrict__ sb3,
    float* __restrict__ filt) {
    __shared__ float m[8][64], f1[8][32], f2[8][32], raw[8][16], nrm[8][2];
    int tid = threadIdx.x;
    for (int i = tid; i < 512; i += 256) m[i >> 6][i & 63] = bm[i];
    __syncthreads();
    {
        int b = tid >> 5, h = tid & 31;
        float s = sb1[h];
        for (int c = 0; c < 64; ++c) s += m[b][c] * sw1[h*64+c];
        f1[b][h] = gelu(s);
    }
    __syncthreads();
    {
        int b = tid >> 5, h = tid & 31;
        float s = sb2[h];
        for (int k = 0; k < 32; ++k) s += f1[b][k] * sw2[h*32+k];
        f2[b][h] = gelu(s);
    }
    __syncthreads();
    if (tid < 128) {
        int b = tid >> 4, j = tid & 15;
        float s = sb3[j];
        for (int k = 0; k < 32; ++k) s += f2[b][k] * sw3[j*32+k];
        raw[b][j] = s;
    }
    __syncthreads();
    if (tid < 16) {
        int b = tid >> 1, half = tid & 1;
        float s = 0.f;
        for (int j = 0; j < 8; ++j) { float v = raw[b][half*8+j]; s += v*v; }
        nrm[b][half] = sqrtf(s);
    }
    __syncthreads();
    if (tid < 16) {
        int half = tid >> 3;
        float s = 0.f;
        for (int b = 0; b < 8; ++b) s += raw[b][tid] / nrm[b][half];
        filt[tid] = s * 0.125f;
    }
}

__global__ __launch_bounds__(256) void wconv_k(const float* __restrict__ ap,
    const float* __restrict__ filt, float* __restrict__ apOut,
    float* __restrict__ stacked, int lev) {
    __shared__ float f[16];
    if (threadIdx.x < 16) f[threadIdx.x] = filt[threadIdx.x];
    __syncthreads();
    size_t idx = (size_t)blockIdx.x * 256 + threadIdx.x;
    int l = (int)(idx & 2047);
    size_t bc = idx >> 11;
    int c = (int)(bc & 63), b = (int)(bc >> 6);
    const float* row = ap + (bc << 11);
    float lo = 0.f, hi = 0.f;
    #pragma unroll
    for (int k = 0; k < 8; ++k) {
        int mI = l + k - 3;
        mI = mI < 0 ? -mI : (mI >= L ? 2*L - 2 - mI : mI);
        float v = row[mI];
        lo += v * f[k];
        hi += v * f[8+k];
    }
    apOut[idx] = lo;
    stacked[((size_t)b * CS + (size_t)(lev+1) * 64 + c) * L + l] = hi;
}

__global__ __launch_bounds__(256) void copyx_k(const float* __restrict__ x, float* __restrict__ st) {
    size_t i = (size_t)blockIdx.x * 256 + threadIdx.x;
    size_t b = i >> 17, rem = i & 131071;
    st[b * ((size_t)CS*L) + rem] = x[i];
}

__global__ __launch_bounds__(256) void copy4_k(const float* __restrict__ s, float* __restrict__ d) {
    size_t i = (size_t)blockIdx.x * 256 + threadIdx.x;
    ((float4*)d)[i] = ((const float4*)s)[i];
}

// stacked fp32 [b][c][l] -> yb bf16 [b][l][c]  (64x64 LDS tile transpose)
__global__ __launch_bounds__(256) void tinit_k(const float* __restrict__ st, u16* __restrict__ yb) {
    __shared__ float t[64][65];
    const int tid = threadIdx.x;
    const int l0 = blockIdx.x * 64, c0 = blockIdx.y * 64, b = blockIdx.z;
    #pragma unroll
    for (int k = 0; k < 16; ++k) {
        int c = k * 4 + (tid >> 6), l = tid & 63;
        t[c][l] = st[((size_t)b*CS + c0 + c) * L + l0 + l];
    }
    __syncthreads();
    #pragma unroll
    for (int k = 0; k < 16; ++k) {
        int p = k * 4 + (tid >> 6), ch = tid & 63;
        yb[((size_t)b * L + l0 + p) * 256 + c0 + ch] = f2b(t[ch][p]);
    }
}

__global__ void ecfin_k(const double* __restrict__ inner, float* __restrict__ out) {
    double s = 0.0;
    for (int b = 0; b < 8; ++b) s += inner[b] * inner[b];
    out[BCSL] = (float)(s / 8.0);
}

extern "C" void kernel_launch(void* const* d_in, const int* in_sizes, int n_in,
                              void* d_out, int out_size, void* d_ws, size_t ws_size,
                              hipStream_t stream) {
    const float* x   = (const float*)d_in[0];
    const float* sw1 = (const float*)d_in[1];
    const float* sb1 = (const float*)d_in[2];
    const float* sw2 = (const float*)d_in[3];
    const float* sb2 = (const float*)d_in[4];
    const float* sw3 = (const float*)d_in[5];
    const float* sb3 = (const float*)d_in[6];
    const float* tw1 = (const float*)d_in[7];
    const float* tb1 = (const float*)d_in[8];
    const float* tw2 = (const float*)d_in[9];
    const float* tb2 = (const float*)d_in[10];
    const float* cw  = (const float*)d_in[11];
    const float* cb  = (const float*)d_in[12];
    const float* k1  = (const float*)d_in[13];
    const float* kb1 = (const float*)d_in[14];
    const float* k2  = (const float*)d_in[15];
    const float* kb2 = (const float*)d_in[16];
    const float* k3  = (const float*)d_in[17];
    const float* kb3 = (const float*)d_in[18];
    float* out = (float*)d_out;

    char* cur = (char*)d_ws;
    auto alloc = [&](size_t bytes) { void* p = cur; cur += (bytes + 255) & ~(size_t)255; return p; };
    float* stacked = (float*)alloc(BCSL * 4);
    float* y       = (float*)alloc(BCSL * 4);
    u16*   yb      = (u16*)  alloc(BCSL * 2);
    u16*   sb[5];
    for (int i = 0; i < 5; ++i) sb[i] = (u16*)alloc(BCSL * 2);
    float* cond  = (float*)alloc(3200 * 4);
    float* bmax  = (float*)alloc(512 * 4);
    float* filt  = (float*)alloc(16 * 4);
    double* inner = (double*)alloc(8 * 8);
    u16* wp1 = (u16*)alloc(49152 * 2);
    u16* wp2 = (u16*)alloc(12288 * 2);
    u16* wp3 = (u16*)alloc(49152 * 2);

    u16 *s1b = sb[0], *s2b = sb[1], *s3b = sb[2], *s4b = sb[3], *s5b = sb[4];

    hipMemsetAsync(inner, 0, 8 * sizeof(double), stream);

    prep_k<<<192, 256, 0, stream>>>(k1, wp1, CS, C);
    prep_k<<<48,  256, 0, stream>>>(k2, wp2, C,  C);
    prep_k<<<192, 256, 0, stream>>>(k3, wp3, C,  CS);
    cond25_k<<<25, 128, 0, stream>>>(tw1, tb1, tw2, tb2, cw, cb, cond);

    // wavelet decomposition (s1b/s2b regions as fp32 scratch: BCL*4 = 4.2MB <= 8.4MB)
    copyx_k<<<4096, 256, 0, stream>>>(x, stacked);
    const float* apIn = x;
    float* apBuf[2] = {(float*)s1b, (float*)s2b};
    for (int lev = 0; lev < 3; ++lev) {
        rowmax_k<<<512, 256, 0, stream>>>(apIn, bmax);
        mlp_k<<<1, 256, 0, stream>>>(bmax, sw1, sb1, sw2, sb2, sw3, sb3, filt);
        float* apOut = apBuf[lev & 1];
        wconv_k<<<4096, 256, 0, stream>>>(apIn, filt, apOut, stacked, lev);
        apIn = apOut;
    }
    copy4_k<<<4096, 256, 0, stream>>>(stacked, y);
    tinit_k<<<dim3(32, 4, 8), 256, 0, stream>>>(stacked, yb);

    const float hs = HS;
    dim3 cg(64, 8);
    #define LAUNCH(NC, EPI, CIN, TIX, OUTSB, OUTP, STK) \
        fused_k<NC, EPI><<<cg, 256, 0, stream>>>(CIN, wp1, kb1, wp2, kb2, wp3, kb3, \
            cond, TIX, OUTSB, y, yb, s1b, s3b, s4b, s5b, OUTP, STK, inner)

    for (int i = 0; i < 4; ++i) {
        ComboB cA{}; cA.p[0] = yb;
        LAUNCH(1, 0, cA, i*6+0, s1b, nullptr, nullptr);

        ComboB cB{}; cB.p[0] = yb; cB.p[1] = s1b; cB.c[1] = hs*(1.f/5.f);
        LAUNCH(2, 0, cB, i*6+1, s2b, nullptr, nullptr);

        ComboB cC{}; cC.p[0] = yb;
        cC.p[1] = s1b; cC.c[1] = hs*(3.f/40.f);
        cC.p[2] = s2b; cC.c[2] = hs*(9.f/40.f);
        LAUNCH(3, 0, cC, i*6+2, s3b, nullptr, nullptr);

        ComboB cD{}; cD.p[0] = yb;
        cD.p[1] = s1b; cD.c[1] = hs*(44.f/45.f);
        cD.p[2] = s2b; cD.c[2] = -hs*(56.f/15.f);
        cD.p[3] = s3b; cD.c[3] = hs*(32.f/9.f);
        LAUNCH(4, 0, cD, i*6+3, s4b, nullptr, nullptr);

        ComboB cE{}; cE.p[0] = yb;
        cE.p[1] = s1b; cE.c[1] = hs*(19372.f/6561.f);
        cE.p[2] = s2b; cE.c[2] = -hs*(25360.f/2187.f);
        cE.p[3] = s3b; cE.c[3] = hs*(64448.f/6561.f);
        cE.p[4] = s4b; cE.c[4] = -hs*(212.f/729.f);
        LAUNCH(5, 0, cE, i*6+4, s5b, nullptr, nullptr);

        ComboB cF{}; cF.p[0] = yb;
        cF.p[1] = s1b; cF.c[1] = hs*(9017.f/3168.f);
        cF.p[2] = s2b; cF.c[2] = -hs*(355.f/33.f);
        cF.p[3] = s3b; cF.c[3] = hs*(46732.f/5247.f);
        cF.p[4] = s4b; cF.c[4] = hs*(49.f/176.f);
        cF.p[5] = s5b; cF.c[5] = -hs*(5103.f/18656.f);
        if (i < 3) {
            LAUNCH(6, 1, cF, i*6+5, nullptr, nullptr, nullptr);   // y + yb update
        } else {
            LAUNCH(6, 2, cF, i*6+5, nullptr, out, nullptr);       // yb update + gather (y store dropped)
        }
    }

    // dx = ode_f(1.0, yb), ecloss fused (dx never stored)
    ComboB cZ{}; cZ.p[0] = yb;
    LAUNCH(1, 3, cZ, 24, nullptr, nullptr, stacked);
    ecfin_k<<<1, 1, 0, stream>>>(inner, out);
    #undef LAUNCH
}

// Round 5
// 712.043 us; speedup vs baseline: 10.0375x; 1.0891x over previous
//
#include <hip/hip_runtime.h>
#include <math.h>

#define B 8
#define C 64
#define L 2048
#define CS 256
#define BCL  (B*C*L)    // 1048576
#define BCSL (B*CS*L)   // 4194304
#define HS 0.25f

typedef unsigned short u16;
typedef unsigned int   u32;
typedef __attribute__((ext_vector_type(8))) short sh8;
typedef __attribute__((ext_vector_type(4))) float f4;
typedef __attribute__((ext_vector_type(8))) unsigned short us8;
typedef __attribute__((ext_vector_type(4))) unsigned short us4;

__device__ __forceinline__ float gelu(float x) {
    return 0.5f * x * (1.0f + erff(x * 0.70710678118654752440f));
}
__device__ __forceinline__ u16 f2b(float f) {
    u32 u = __float_as_uint(f);
    u32 r = u + 0x7FFFu + ((u >> 16) & 1u);
    return (u16)(r >> 16);
}
__device__ __forceinline__ float b2f(u16 h) {
    return __uint_as_float(((u32)h) << 16);
}

struct ComboB { const u16* p[6]; float c[6]; };

// ---------- weight prep: fp32 [oc][ic][k] -> bf16 A-frag order ----------
__global__ __launch_bounds__(256) void prep_k(const float* __restrict__ w,
        u16* __restrict__ dst, int IC, int OC) {
    int idx = blockIdx.x * 256 + threadIdx.x;
    int OCG = OC >> 4;
    int j = idx & 7, lane = (idx >> 3) & 63, t = idx >> 9;
    int ocg = t % OCG, c = t / OCG;
    int oc = ocg * 16 + (lane & 15);
    int K = c * 32 + ((lane >> 4) & 3) * 8 + j;
    int kk = K / IC, ic = K % IC;
    dst[idx] = f2b(w[((size_t)oc * IC + ic) * 3 + kk]);
}

// ---------- all 25 cond vectors ----------
__global__ void cond25_k(const float* __restrict__ tw1, const float* __restrict__ tb1,
                         const float* __restrict__ tw2, const float* __restrict__ tb2,
                         const float* __restrict__ cw, const float* __restrict__ cb,
                         float* __restrict__ condall) {
    __shared__ float te1[16], te2[16];
    int tix = blockIdx.x;
    int tid = threadIdx.x;
    double add[6] = {0.0, 0.25/5.0, 3.0*0.25/10.0, 4.0*0.25/5.0, 8.0*0.25/9.0, 0.25};
    float t = (tix == 24) ? 1.0f : (float)((double)(tix / 6) * 0.25 + add[tix % 6]);
    if (tid < 16) te1[tid] = gelu(t * tw1[tid] + tb1[tid]);
    __syncthreads();
    if (tid < 16) {
        float s = tb2[tid];
        for (int k = 0; k < 16; ++k) s += te1[k] * tw2[tid*16+k];
        te2[tid] = s;
    }
    __syncthreads();
    float s = cb[tid];
    for (int j = 0; j < 16; ++j) s += te2[j] * cw[tid*16+j];
    condall[tix*128 + tid] = s;
}

// ---------- fused ode_f: conv1(FiLM,GELU) -> conv2(GELU) -> conv3 ----------
// 16-position tiles, grid (128, 8). Inputs bf16 transposed [b][pos][ch].
// Halo chain: input 22 pos (g0=l0-3) -> h1 20 -> h2 18 -> out 16.
// EPI: 0 = store s (bf16 transposed); 1 = y update (+yb); 2 = yb update + permuted out; 3 = ecloss
template<int NC, int EPI>
__global__ __launch_bounds__(256) void fused_k(ComboB in,
        const u16* __restrict__ wp1, const float* __restrict__ kb1,
        const u16* __restrict__ wp2, const float* __restrict__ kb2,
        const u16* __restrict__ wp3, const float* __restrict__ kb3,
        const float* __restrict__ condall, int tix,
        u16* __restrict__ outSb,
        float* __restrict__ y, u16* __restrict__ yb,
        float* __restrict__ outp, const float* __restrict__ stacked,
        double* __restrict__ inner)
{
    __shared__ u16 xs1[34][264];   // [pos][ic] conv1 input; rows 0..21 staged, 22..33 zero
    __shared__ u16 h1t[34][72];    // [pos][oc] conv1 output; rows >=20 zero
    __shared__ u16 h2t[18][72];    // [pos][oc] conv2 output
    __shared__ u16 ypart[16][264]; // y-update partial (EPI 1/2)
    __shared__ double sred[4];
    const int tid = threadIdx.x;
    const int l0  = blockIdx.x * 16;
    const int b   = blockIdx.y;
    const int g0  = l0 - 3;

    const float cy1 = HS*(35.f/384.f), cy3 = HS*(500.f/1113.f),
                cy4 = HS*(125.f/192.f), cy5 = -HS*(2187.f/6784.f),
                cy6 = HS*(11.f/84.f);

    // zero never-written-but-read rows
    for (int i = tid; i < 12*264; i += 256) xs1[22 + i/264][i%264] = 0;
    if (tid < 144) h1t[32 + tid/72][tid%72] = 0;

    // stage combo (bf16 transposed in) -> bf16 transposed LDS; fully coalesced
    for (int idx = tid; idx < 22*32; idx += 256) {
        int r = idx >> 5, c8 = idx & 31;
        int gl = g0 + r;
        us8 val;
        if (gl >= 0 && gl < L) {
            size_t a = ((size_t)b * L + gl) * 256 + c8 * 8;
            us8 v0 = *(const us8*)(in.p[0] + a);
            if (NC == 1) {
                val = v0;
            } else {
                float f[8];
                float yp[8];
                #pragma unroll
                for (int j = 0; j < 8; ++j) { f[j] = b2f(v0[j]); yp[j] = 0.f; }
                #pragma unroll
                for (int t = 1; t < NC; ++t) {
                    us8 vt = *(const us8*)(in.p[t] + a);
                    #pragma unroll
                    for (int j = 0; j < 8; ++j) {
                        float bv = b2f(vt[j]);
                        f[j] += in.c[t] * bv;
                        if ((EPI == 1 || EPI == 2) && (t == 1 || t == 3 || t == 4 || t == 5)) {
                            float cy = (t == 1) ? cy1 : (t == 3) ? cy3 : (t == 4) ? cy4 : cy5;
                            yp[j] += cy * bv;
                        }
                    }
                }
                #pragma unroll
                for (int j = 0; j < 8; ++j) val[j] = f2b(f[j]);
                if ((EPI == 1 || EPI == 2) && r >= 3 && r < 19) {
                    us8 ypk;
                    #pragma unroll
                    for (int j = 0; j < 8; ++j) ypk[j] = f2b(yp[j]);
                    *(us8*)&ypart[r - 3][c8 * 8] = ypk;
                }
            }
        } else {
            #pragma unroll
            for (int j = 0; j < 8; ++j) val[j] = 0;
        }
        *(us8*)&xs1[r][c8 * 8] = val;
    }
    __syncthreads();

    const int wave = tid >> 6, lane = tid & 63;
    const int nlo = lane & 15, quad = lane >> 4;

    // ---- conv1: M=16/wave, N=32, K=768 ----
    f4 a1[2];
    a1[0] = f4{0.f,0.f,0.f,0.f}; a1[1] = a1[0];
    {
        const sh8* w1 = (const sh8*)wp1;
        for (int c = 0; c < 24; ++c) {
            int kk = c >> 3, ic0 = (c & 7) << 5;
            sh8 A = w1[(c*4 + wave)*64 + lane];
            #pragma unroll
            for (int nf = 0; nf < 2; ++nf) {
                sh8 Bv = *(const sh8*)&xs1[nf*16 + nlo + kk][ic0 + quad*8];
                a1[nf] = __builtin_amdgcn_mfma_f32_16x16x32_bf16(A, Bv, a1[nf], 0, 0, 0);
            }
        }
    }
    {
        const float* cd = condall + tix*128;
        #pragma unroll
        for (int nf = 0; nf < 2; ++nf) {
            int p = nf*16 + nlo;
            int gp = l0 - 2 + p;
            bool ok = (p < 20) && (gp >= 0) && (gp < L);
            #pragma unroll
            for (int reg = 0; reg < 4; ++reg) {
                int oc = wave*16 + quad*4 + reg;
                float v = (1.f + cd[oc]) * (a1[nf][reg] + kb1[oc]) + cd[64+oc];
                h1t[p][oc] = ok ? f2b(gelu(v)) : (u16)0;
            }
        }
    }
    __syncthreads();

    // ---- conv2: M=16/wave, N=32, K=192 ----
    f4 a2[2];
    a2[0] = f4{0.f,0.f,0.f,0.f}; a2[1] = a2[0];
    {
        const sh8* w2 = (const sh8*)wp2;
        #pragma unroll
        for (int c = 0; c < 6; ++c) {
            int kk = c >> 1, ic0 = (c & 1) << 5;
            sh8 A = w2[(c*4 + wave)*64 + lane];
            #pragma unroll
            for (int nf = 0; nf < 2; ++nf) {
                sh8 Bv = *(const sh8*)&h1t[nf*16 + nlo + kk][ic0 + quad*8];
                a2[nf] = __builtin_amdgcn_mfma_f32_16x16x32_bf16(A, Bv, a2[nf], 0, 0, 0);
            }
        }
    }
    {
        #pragma unroll
        for (int nf = 0; nf < 2; ++nf) {
            int q = nf*16 + nlo;
            if (q < 18) {
                int gq = l0 - 1 + q;
                bool ok = (gq >= 0) && (gq < L);
                #pragma unroll
                for (int reg = 0; reg < 4; ++reg) {
                    int oc = wave*16 + quad*4 + reg;
                    h2t[q][oc] = ok ? f2b(gelu(a2[nf][reg] + kb2[oc])) : (u16)0;
                }
            }
        }
    }
    __syncthreads();

    // ---- conv3: M=64/wave, N=16, K=192 ----
    f4 a3[4];
    #pragma unroll
    for (int mf = 0; mf < 4; ++mf) a3[mf] = f4{0.f,0.f,0.f,0.f};
    {
        const sh8* w3 = (const sh8*)wp3;
        #pragma unroll
        for (int c = 0; c < 6; ++c) {
            int kk = c >> 1, ic0 = (c & 1) << 5;
            sh8 B0 = *(const sh8*)&h2t[nlo + kk][ic0 + quad*8];
            #pragma unroll
            for (int mf = 0; mf < 4; ++mf) {
                sh8 A = w3[(c*16 + wave*4 + mf)*64 + lane];
                a3[mf] = __builtin_amdgcn_mfma_f32_16x16x32_bf16(A, B0, a3[mf], 0, 0, 0);
            }
        }
    }

    // ---- epilogue ----
    const int pos = l0 + nlo;
    if (EPI == 3) {
        double acc = 0.0;
        #pragma unroll
        for (int mf = 0; mf < 4; ++mf)
            #pragma unroll
            for (int reg = 0; reg < 4; ++reg) {
                int oc = (wave*4 + mf)*16 + quad*4 + reg;
                size_t idx = ((size_t)b*CS + oc)*L + pos;
                float dx = a3[mf][reg] + kb3[oc];
                acc += (double)stacked[idx] * (double)dx;
            }
        #pragma unroll
        for (int off = 32; off > 0; off >>= 1) acc += __shfl_down(acc, off, 64);
        if (lane == 0) sred[wave] = acc;
        __syncthreads();
        if (tid == 0) atomicAdd(&inner[b], sred[0] + sred[1] + sred[2] + sred[3]);
    } else if (EPI == 0) {
        #pragma unroll
        for (int mf = 0; mf < 4; ++mf) {
            int baseoc = (wave*4 + mf)*16 + quad*4;
            us4 pk;
            #pragma unroll
            for (int reg = 0; reg < 4; ++reg)
                pk[reg] = f2b(a3[mf][reg] + kb3[baseoc + reg]);
            *(us4*)(outSb + ((size_t)b*L + pos)*256 + baseoc) = pk;
        }
    } else {
        #pragma unroll
        for (int mf = 0; mf < 4; ++mf) {
            int baseoc = (wave*4 + mf)*16 + quad*4;
            us4 yp4 = *(const us4*)&ypart[nlo][baseoc];
            us4 pk;
            #pragma unroll
            for (int reg = 0; reg < 4; ++reg) {
                int oc = baseoc + reg;
                size_t idx = ((size_t)b*CS + oc)*L + pos;
                float s6 = a3[mf][reg] + kb3[oc];
                float yv = y[idx] + b2f(yp4[reg]) + cy6 * s6;
                pk[reg] = f2b(yv);
                if (EPI == 1) y[idx] = yv;
                if (EPI == 2) {
                    size_t oidx = (((size_t)(oc >> 6)*B + b)*64 + (oc & 63))*L + pos;
                    outp[oidx] = yv;
                }
            }
            *(us4*)(yb + ((size_t)b*L + pos)*256 + baseoc) = pk;
        }
    }
}

// ---------- wavelet part ----------
__global__ __launch_bounds__(256) void rowmax_k(const float* __restrict__ a, float* __restrict__ bm) {
    __shared__ float red[256];
    int row = blockIdx.x;
    const float* p = a + (size_t)row * L;
    float m = -1e30f;
    for (int t = threadIdx.x; t < L; t += 256) m = fmaxf(m, p[t]);
    red[threadIdx.x] = m;
    __syncthreads();
    for (int s = 128; s > 0; s >>= 1) {
        if (threadIdx.x < s) red[threadIdx.x] = fmaxf(red[threadIdx.x], red[threadIdx.x + s]);
        __syncthreads();
    }
    if (threadIdx.x == 0) bm[row] = red[0];
}

__global__ __launch_bounds__(256) void mlp_k(const float* __restrict__ bm,
    const float* __restrict__ sw1, const float* __restrict__ sb1,
    const float* __restrict__ sw2, const float* __restrict__ sb2,
    const float* __restrict__ sw3, const float* __restrict__ sb3,
    float* __restrict__ filt) {
    __shared__ float m[8][64], f1[8][32], f2[8][32], raw[8][16], nrm[8][2];
    int tid = threadIdx.x;
    for (int i = tid; i < 512; i += 256) m[i >> 6][i & 63] = bm[i];
    __syncthreads();
    {
        int b = tid >> 5, h = tid & 31;
        float s = sb1[h];
        for (int c = 0; c < 64; ++c) s += m[b][c] * sw1[h*64+c];
        f1[b][h] = gelu(s);
    }
    __syncthreads();
    {
        int b = tid >> 5, h = tid & 31;
        float s = sb2[h];
        for (int k = 0; k < 32; ++k) s += f1[b][k] * sw2[h*32+k];
        f2[b][h] = gelu(s);
    }
    __syncthreads();
    if (tid < 128) {
        int b = tid >> 4, j = tid & 15;
        float s = sb3[j];
        for (int k = 0; k < 32; ++k) s += f2[b][k] * sw3[j*32+k];
        raw[b][j] = s;
    }
    __syncthreads();
    if (tid < 16) {
        int b = tid >> 1, half = tid & 1;
        float s = 0.f;
        for (int j = 0; j < 8; ++j) { float v = raw[b][half*8+j]; s += v*v; }
        nrm[b][half] = sqrtf(s);
    }
    __syncthreads();
    if (tid < 16) {
        int half = tid >> 3;
        float s = 0.f;
        for (int b = 0; b < 8; ++b) s += raw[b][tid] / nrm[b][half];
        filt[tid] = s * 0.125f;
    }
}

__global__ __launch_bounds__(256) void wconv_k(const float* __restrict__ ap,
    const float* __restrict__ filt, float* __restrict__ apOut,
    float* __restrict__ stacked, int lev) {
    __shared__ float f[16];
    if (threadIdx.x < 16) f[threadIdx.x] = filt[threadIdx.x];
    __syncthreads();
    size_t idx = (size_t)blockIdx.x * 256 + threadIdx.x;
    int l = (int)(idx & 2047);
    size_t bc = idx >> 11;
    int c = (int)(bc & 63), b = (int)(bc >> 6);
    const float* row = ap + (bc << 11);
    float lo = 0.f, hi = 0.f;
    #pragma unroll
    for (int k = 0; k < 8; ++k) {
        int mI = l + k - 3;
        mI = mI < 0 ? -mI : (mI >= L ? 2*L - 2 - mI : mI);
        float v = row[mI];
        lo += v * f[k];
        hi += v * f[8+k];
    }
    apOut[idx] = lo;
    stacked[((size_t)b * CS + (size_t)(lev+1) * 64 + c) * L + l] = hi;
}

__global__ __launch_bounds__(256) void copyx_k(const float* __restrict__ x, float* __restrict__ st) {
    size_t i = (size_t)blockIdx.x * 256 + threadIdx.x;
    size_t b = i >> 17, rem = i & 131071;
    st[b * ((size_t)CS*L) + rem] = x[i];
}

// stacked fp32 [b][c][l] -> y fp32 (copy) + yb bf16 [b][l][c] (transpose)
__global__ __launch_bounds__(256) void tinit_k(const float* __restrict__ st,
        float* __restrict__ y, u16* __restrict__ yb) {
    __shared__ float t[64][65];
    const int tid = threadIdx.x;
    const int l0 = blockIdx.x * 64, c0 = blockIdx.y * 64, b = blockIdx.z;
    #pragma unroll
    for (int k = 0; k < 16; ++k) {
        int c = k * 4 + (tid >> 6), l = tid & 63;
        size_t idx = ((size_t)b*CS + c0 + c) * L + l0 + l;
        float v = st[idx];
        y[idx] = v;
        t[c][l] = v;
    }
    __syncthreads();
    #pragma unroll
    for (int k = 0; k < 16; ++k) {
        int p = k * 4 + (tid >> 6), ch = tid & 63;
        yb[((size_t)b * L + l0 + p) * 256 + c0 + ch] = f2b(t[ch][p]);
    }
}

__global__ void ecfin_k(const double* __restrict__ inner, float* __restrict__ out) {
    double s = 0.0;
    for (int b = 0; b < 8; ++b) s += inner[b] * inner[b];
    out[BCSL] = (float)(s / 8.0);
}

extern "C" void kernel_launch(void* const* d_in, const int* in_sizes, int n_in,
                              void* d_out, int out_size, void* d_ws, size_t ws_size,
                              hipStream_t stream) {
    const float* x   = (const float*)d_in[0];
    const float* sw1 = (const float*)d_in[1];
    const float* sb1 = (const float*)d_in[2];
    const float* sw2 = (const float*)d_in[3];
    const float* sb2 = (const float*)d_in[4];
    const float* sw3 = (const float*)d_in[5];
    const float* sb3 = (const float*)d_in[6];
    const float* tw1 = (const float*)d_in[7];
    const float* tb1 = (const float*)d_in[8];
    const float* tw2 = (const float*)d_in[9];
    const float* tb2 = (const float*)d_in[10];
    const float* cw  = (const float*)d_in[11];
    const float* cb  = (const float*)d_in[12];
    const float* k1  = (const float*)d_in[13];
    const float* kb1 = (const float*)d_in[14];
    const float* k2  = (const float*)d_in[15];
    const float* kb2 = (const float*)d_in[16];
    const float* k3  = (const float*)d_in[17];
    const float* kb3 = (const float*)d_in[18];
    float* out = (float*)d_out;

    char* cur = (char*)d_ws;
    auto alloc = [&](size_t bytes) { void* p = cur; cur += (bytes + 255) & ~(size_t)255; return p; };
    float* stacked = (float*)alloc(BCSL * 4);
    float* y       = (float*)alloc(BCSL * 4);
    u16*   yb      = (u16*)  alloc(BCSL * 2);
    u16*   sbuf[5];
    for (int i = 0; i < 5; ++i) sbuf[i] = (u16*)alloc(BCSL * 2);
    float* cond  = (float*)alloc(3200 * 4);
    float* bmax  = (float*)alloc(512 * 4);
    float* filt  = (float*)alloc(16 * 4);
    double* inner = (double*)alloc(8 * 8);
    u16* wp1 = (u16*)alloc(49152 * 2);
    u16* wp2 = (u16*)alloc(12288 * 2);
    u16* wp3 = (u16*)alloc(49152 * 2);

    u16 *s1b = sbuf[0], *s2b = sbuf[1], *s3b = sbuf[2], *s4b = sbuf[3], *s5b = sbuf[4];

    hipMemsetAsync(inner, 0, 8 * sizeof(double), stream);

    prep_k<<<192, 256, 0, stream>>>(k1, wp1, CS, C);
    prep_k<<<48,  256, 0, stream>>>(k2, wp2, C,  C);
    prep_k<<<192, 256, 0, stream>>>(k3, wp3, C,  CS);
    cond25_k<<<25, 128, 0, stream>>>(tw1, tb1, tw2, tb2, cw, cb, cond);

    // wavelet decomposition (s1b/s2b regions as fp32 scratch: BCL*4 = 4.2MB <= 8.4MB)
    copyx_k<<<4096, 256, 0, stream>>>(x, stacked);
    const float* apIn = x;
    float* apBuf[2] = {(float*)s1b, (float*)s2b};
    for (int lev = 0; lev < 3; ++lev) {
        rowmax_k<<<512, 256, 0, stream>>>(apIn, bmax);
        mlp_k<<<1, 256, 0, stream>>>(bmax, sw1, sb1, sw2, sb2, sw3, sb3, filt);
        float* apOut = apBuf[lev & 1];
        wconv_k<<<4096, 256, 0, stream>>>(apIn, filt, apOut, stacked, lev);
        apIn = apOut;
    }
    tinit_k<<<dim3(32, 4, 8), 256, 0, stream>>>(stacked, y, yb);

    const float hs = HS;
    dim3 cg(128, 8);
    #define LAUNCH(NC, EPI, CIN, TIX, OUTSB, OUTP, STK) \
        fused_k<NC, EPI><<<cg, 256, 0, stream>>>(CIN, wp1, kb1, wp2, kb2, wp3, kb3, \
            cond, TIX, OUTSB, y, yb, OUTP, STK, inner)

    for (int i = 0; i < 4; ++i) {
        ComboB cA{}; cA.p[0] = yb;
        LAUNCH(1, 0, cA, i*6+0, s1b, nullptr, nullptr);

        ComboB cB{}; cB.p[0] = yb; cB.p[1] = s1b; cB.c[1] = hs*(1.f/5.f);
        LAUNCH(2, 0, cB, i*6+1, s2b, nullptr, nullptr);

        ComboB cC{}; cC.p[0] = yb;
        cC.p[1] = s1b; cC.c[1] = hs*(3.f/40.f);
        cC.p[2] = s2b; cC.c[2] = hs*(9.f/40.f);
        LAUNCH(3, 0, cC, i*6+2, s3b, nullptr, nullptr);

        ComboB cD{}; cD.p[0] = yb;
        cD.p[1] = s1b; cD.c[1] = hs*(44.f/45.f);
        cD.p[2] = s2b; cD.c[2] = -hs*(56.f/15.f);
        cD.p[3] = s3b; cD.c[3] = hs*(32.f/9.f);
        LAUNCH(4, 0, cD, i*6+3, s4b, nullptr, nullptr);

        ComboB cE{}; cE.p[0] = yb;
        cE.p[1] = s1b; cE.c[1] = hs*(19372.f/6561.f);
        cE.p[2] = s2b; cE.c[2] = -hs*(25360.f/2187.f);
        cE.p[3] = s3b; cE.c[3] = hs*(64448.f/6561.f);
        cE.p[4] = s4b; cE.c[4] = -hs*(212.f/729.f);
        LAUNCH(5, 0, cE, i*6+4, s5b, nullptr, nullptr);

        ComboB cF{}; cF.p[0] = yb;
        cF.p[1] = s1b; cF.c[1] = hs*(9017.f/3168.f);
        cF.p[2] = s2b; cF.c[2] = -hs*(355.f/33.f);
        cF.p[3] = s3b; cF.c[3] = hs*(46732.f/5247.f);
        cF.p[4] = s4b; cF.c[4] = hs*(49.f/176.f);
        cF.p[5] = s5b; cF.c[5] = -hs*(5103.f/18656.f);
        if (i < 3) {
            LAUNCH(6, 1, cF, i*6+5, nullptr, nullptr, nullptr);   // y + yb update
        } else {
            LAUNCH(6, 2, cF, i*6+5, nullptr, out, nullptr);       // yb update + gather
        }
    }

    // dx = ode_f(1.0, yb), ecloss fused (dx never stored)
    ComboB cZ{}; cZ.p[0] = yb;
    LAUNCH(1, 3, cZ, 24, nullptr, nullptr, stacked);
    ecfin_k<<<1, 1, 0, stream>>>(inner, out);
    #undef LAUNCH
}